// Round 1
// baseline (216.112 us; speedup 1.0000x reference)
//
#include <hip/hip_runtime.h>
#include <cstdint>
#include <cstddef>

typedef unsigned short u16;
typedef __attribute__((ext_vector_type(8))) __bf16 bf16x8;
typedef __attribute__((ext_vector_type(16))) float f32x16;

#define LPOS 4096
#define CDIM 256

__device__ __forceinline__ unsigned f2bfbits(float x) {
  union { float f; unsigned u; } v; v.f = x;
  return (v.u + 0x7FFFu + ((v.u >> 16) & 1u)) >> 16;
}
__device__ __forceinline__ unsigned packbf(float a, float b) {
  return f2bfbits(a) | (f2bfbits(b) << 16);
}

// ---------------- P1: per-position mean + inv-L2-norm ----------------
// t -> (arr, b, pos); layout of mArr/iArr = [3][2][4096]
__global__ void norm_stats(const float* __restrict__ t_in,
                           const float* __restrict__ s_in,
                           const float* __restrict__ r_in,
                           float* __restrict__ mArr, float* __restrict__ iArr) {
  int t = blockIdx.x * 256 + threadIdx.x;      // 0..24575
  int arr = t >> 13;                            // 0..2
  int rem = t & 8191;
  int b = rem >> 12;
  int pos = rem & 4095;
  const float* inp = (arr == 0 ? t_in : arr == 1 ? s_in : r_in);
  const float* col = inp + (size_t)b * CDIM * LPOS + pos;
  float sum = 0.f, sumsq = 0.f;
#pragma unroll 8
  for (int c = 0; c < CDIM; ++c) {
    float v = col[(size_t)c * LPOS];
    sum += v; sumsq += v * v;
  }
  float mean = sum * (1.0f / CDIM);
  float nsq = sumsq - sum * sum * (1.0f / CDIM);
  float inv = rsqrtf(fmaxf(nsq, 1e-20f));
  mArr[t] = mean;
  iArr[t] = inv;
}

// ---------------- P2: normalize + transpose + cast to bf16 [B][L][C] --------
__global__ void norm_transpose(const float* __restrict__ t_in,
                               const float* __restrict__ s_in,
                               const float* __restrict__ r_in,
                               const float* __restrict__ mArr,
                               const float* __restrict__ iArr,
                               u16* __restrict__ qn, u16* __restrict__ ksn,
                               u16* __restrict__ krn) {
  int idx = blockIdx.x;
  int ab = idx >> 8;            // 0..5
  int arr = ab >> 1, b = ab & 1;
  int rr = idx & 255;
  int lt = rr & 63, ct = rr >> 6;
  int l0 = lt * 64, c0 = ct * 64;
  const float* inp = (arr == 0 ? t_in : arr == 1 ? s_in : r_in) + (size_t)b * CDIM * LPOS;
  u16* outp = (arr == 0 ? qn : arr == 1 ? ksn : krn) + (size_t)b * LPOS * CDIM;
  const float* m = mArr + (arr * 2 + b) * LPOS;
  const float* iv = iArr + (arr * 2 + b) * LPOS;
  __shared__ float lk[64][65];
  int t = threadIdx.x;
  int cq = t >> 6, ll = t & 63;
#pragma unroll
  for (int r2 = 0; r2 < 16; ++r2) {
    int cr = cq + r2 * 4;
    lk[cr][ll] = inp[(size_t)(c0 + cr) * LPOS + l0 + ll];
  }
  __syncthreads();
  int cp = t & 31, lb = t >> 5;
#pragma unroll
  for (int r2 = 0; r2 < 8; ++r2) {
    int l = lb + r2 * 8;
    int pos = l0 + l;
    float mm = m[pos], vv = iv[pos];
    float v0 = (lk[2 * cp][l] - mm) * vv;
    float v1 = (lk[2 * cp + 1][l] - mm) * vv;
    unsigned pk = packbf(v0, v1);
    *(unsigned*)&outp[(size_t)pos * CDIM + c0 + 2 * cp] = pk;
  }
}

// ---------------- P3: build combined V tensors (bf16, [C_v][L]) -------------
// vs: [2][32][4096]   ch: 0..3 src_feats, 4 ones, 5..31 zero
// vr: [2][192][4096]  ch: 0..150 sem, 151..154 ref_feats, 155 ones,
//                         156..159 zero, 160..191 staging pad (unwritten)
__global__ void build_v(const float* __restrict__ sf, const float* __restrict__ rf,
                        const float* __restrict__ sem,
                        u16* __restrict__ vs, u16* __restrict__ vr) {
  int t = blockIdx.x * 256 + threadIdx.x;
  const int NVS = 2 * 32 * 4096;
  if (t < NVS) {
    int b = t >> 17;
    int c = (t >> 12) & 31;
    int j = t & 4095;
    float v = (c < 4) ? sf[((size_t)b * 4 + c) * LPOS + j] : (c == 4 ? 1.0f : 0.0f);
    vs[t] = (u16)f2bfbits(v);
  } else {
    int t2 = t - NVS;
    if (t2 < 2 * 160 * 4096) {
      int b = t2 / (160 * 4096);
      int rr = t2 % (160 * 4096);
      int c = rr >> 12, j = rr & 4095;
      float v = (c < 151) ? sem[((size_t)b * 151 + c) * LPOS + j]
              : (c < 155) ? rf[((size_t)b * 4 + (c - 151)) * LPOS + j]
              : (c == 155) ? 1.0f : 0.0f;
      vr[((size_t)b * 192 + c) * LPOS + j] = (u16)f2bfbits(v);
    }
  }
}

// ---------------- fused flash soft-warp ----------------
// S^T orientation: D[m=j][n=i] = sum_c K[j][c] * Q[i][c]
// PV: D[m=c][n=i]  = sum_j V[c][j] * P[j][i]
template <int CT, bool IS_REF>
__device__ __forceinline__ void flash_body(
    const u16* __restrict__ qb, const u16* __restrict__ kb,
    const u16* __restrict__ vb, float* __restrict__ dst,
    u16* lds_k, u16* lds_v, int wave, int lane, int i_wave, int j_base, int iters) {
  int h = lane >> 5, ln = lane & 31;

  // Q fragments register-resident: B[k=c][n=i], lane n=ln, k = kt*16 + h*8 + t
  bf16x8 qf[16];
  const u16* qrow = qb + (size_t)(i_wave + ln) * CDIM;
#pragma unroll
  for (int kt = 0; kt < 16; ++kt)
    qf[kt] = *(const bf16x8*)(qrow + kt * 16 + h * 8);

  f32x16 O[CT];
#pragma unroll
  for (int c = 0; c < CT; ++c)
#pragma unroll
    for (int t = 0; t < 16; ++t) O[c][t] = 0.0f;

  for (int jt = 0; jt < iters; ++jt) {
    int j0 = j_base + jt * 32;
    __syncthreads();
    // stage K tile [32 j][256 c] bf16, 16B chunks XOR-swizzled by (j&7)
#pragma unroll
    for (int g = 0; g < 4; ++g) {
      int G = wave * 4 + g;
      int j = 2 * G + h;
      int mlog = ln ^ (j & 7);
      uint4 d = *(const uint4*)(kb + (size_t)(j0 + j) * CDIM + mlog * 8);
      *(uint4*)&lds_k[j * CDIM + ln * 8] = d;
    }
    // stage V tile: planes p=0..3 are j-octets; within plane rows are c, 16B each
    if (IS_REF) {
#pragma unroll
      for (int g = 0; g < 3; ++g) {
        int t2 = wave * 3 + g;              // 0..11
        int p = t2 & 3, cc = t2 >> 2;
        int c = cc * 64 + lane;             // 0..191
        uint4 d = *(const uint4*)(vb + (size_t)c * LPOS + j0 + p * 8);
        *(uint4*)&lds_v[p * 1536 + c * 8] = d;
      }
    } else {
      if (wave < 2) {
        int p = wave * 2 + h;
        uint4 d = *(const uint4*)(vb + (size_t)ln * LPOS + j0 + p * 8);
        *(uint4*)&lds_v[p * 256 + ln * 8] = d;
      }
    }
    __syncthreads();

    // QK: S^T tile, A = K (from LDS), B = Q (regs)
    f32x16 S;
#pragma unroll
    for (int t = 0; t < 16; ++t) S[t] = 0.0f;
#pragma unroll
    for (int kt = 0; kt < 16; ++kt) {
      int mphys = (2 * kt + h) ^ (ln & 7);
      bf16x8 ka = *(const bf16x8*)&lds_k[ln * CDIM + mphys * 8];
      S = __builtin_amdgcn_mfma_f32_32x32x16_bf16(ka, qf[kt], S, 0, 0, 0);
    }
    // scores are cosine sims in [-1,1]: exp directly, no max-subtract needed
#pragma unroll
    for (int t = 0; t < 16; ++t) S[t] = __expf(S[t]);

    // P^T C-layout -> PV B-frags via xor-32 lane exchange, cast to bf16
    bf16x8 pb[2];
#pragma unroll
    for (int kt = 0; kt < 2; ++kt) {
      int kbase = kt * 8 + (h ? 4 : 0);   // regs this lane keeps
      int sbase = kt * 8 + (h ? 0 : 4);   // regs the partner needs
      unsigned keep0 = packbf(S[kbase + 0], S[kbase + 1]);
      unsigned keep1 = packbf(S[kbase + 2], S[kbase + 3]);
      unsigned send0 = packbf(S[sbase + 0], S[sbase + 1]);
      unsigned send1 = packbf(S[sbase + 2], S[sbase + 3]);
      unsigned recv0 = (unsigned)__shfl_xor((int)send0, 32, 64);
      unsigned recv1 = (unsigned)__shfl_xor((int)send1, 32, 64);
      union { unsigned u[4]; bf16x8 v; } tmp;
      tmp.u[0] = h ? recv0 : keep0;   // t0,t1
      tmp.u[1] = h ? recv1 : keep1;   // t2,t3
      tmp.u[2] = h ? keep0 : recv0;   // t4,t5
      tmp.u[3] = h ? keep1 : recv1;   // t6,t7
      pb[kt] = tmp.v;
    }

    // PV: A = V (from LDS planes), B = P
#pragma unroll
    for (int ct = 0; ct < CT; ++ct)
#pragma unroll
      for (int kt = 0; kt < 2; ++kt) {
        int p = 2 * kt + h;
        const u16* vp = IS_REF ? &lds_v[p * 1536 + (ct * 32 + ln) * 8]
                               : &lds_v[p * 256 + ln * 8];
        bf16x8 va = *(const bf16x8*)vp;
        O[ct] = __builtin_amdgcn_mfma_f32_32x32x16_bf16(va, pb[kt], O[ct], 0, 0, 0);
      }
  }

  // epilogue: D rows = c, cols = i
  if (IS_REF) {
#pragma unroll
    for (int ct = 0; ct < CT; ++ct)
#pragma unroll
      for (int t = 0; t < 16; ++t) {
        int c = ct * 32 + (t & 3) + 8 * (t >> 2) + 4 * h;
        dst[(size_t)c * LPOS + i_wave + ln] = O[ct][t];
      }
  } else {
#pragma unroll
    for (int t = 0; t < 4; ++t) {
      int c = t + 4 * h;                 // c in 0..7 (only regs 0..3 are c<8)
      dst[(size_t)c * LPOS + i_wave + ln] = O[0][t];
    }
  }
}

__global__ __launch_bounds__(256, 2) void flash(
    const u16* __restrict__ qn, const u16* __restrict__ ksn, const u16* __restrict__ krn,
    const u16* __restrict__ vs, const u16* __restrict__ vr,
    float* __restrict__ nsrc, float* __restrict__ nref, int nchunks) {
  __shared__ u16 lds_k[32 * 256];    // 16 KB
  __shared__ u16 lds_v[4 * 192 * 8]; // 12 KB
  int tid = threadIdx.x;
  int wave = tid >> 6, lane = tid & 63;
  int bpc = 64 * nchunks;
  int idx = blockIdx.x;
  bool is_ref = idx >= bpc;
  int r = is_ref ? idx - bpc : idx;
  int chunk = r >> 6;
  int b = (r >> 5) & 1;
  int wgi = r & 31;
  int jchunk = LPOS / nchunks;
  int j_base = chunk * jchunk;
  int iters = jchunk / 32;
  int i_wave = wgi * 128 + wave * 32;
  const u16* qb = qn + (size_t)b * LPOS * CDIM;
  if (is_ref) {
    flash_body<5, true>(qb, krn + (size_t)b * LPOS * CDIM, vr + (size_t)b * 192 * LPOS,
                        nref + (size_t)(chunk * 2 + b) * 160 * LPOS,
                        lds_k, lds_v, wave, lane, i_wave, j_base, iters);
  } else {
    flash_body<1, false>(qb, ksn + (size_t)b * LPOS * CDIM, vs + (size_t)b * 32 * LPOS,
                         nsrc + (size_t)(chunk * 2 + b) * 8 * LPOS,
                         lds_k, lds_v, wave, lane, i_wave, j_base, iters);
  }
}

// ---------------- finalize: sum chunks, divide by ones-channel --------------
__global__ void finalize(const float* __restrict__ nsrc, const float* __restrict__ nref,
                         float* __restrict__ out, int nchunks) {
  int t = blockIdx.x * 256 + threadIdx.x;
  if (t >= 1302528) return;
  if (t < 32768) {                        // warped_src_feat [2][4][4096]
    int b = t >> 14, c = (t >> 12) & 3, i = t & 4095;
    float num = 0.f, den = 0.f;
    for (int k = 0; k < nchunks; ++k) {
      const float* base = nsrc + ((size_t)(k * 2 + b) * 8) * LPOS;
      num += base[(size_t)c * LPOS + i];
      den += base[(size_t)4 * LPOS + i];
    }
    out[t] = num / den;
  } else if (t < 65536) {                 // warped_ref_feat [2][4][4096]
    int t1 = t - 32768;
    int b = t1 >> 14, c = (t1 >> 12) & 3, i = t1 & 4095;
    float num = 0.f, den = 0.f;
    for (int k = 0; k < nchunks; ++k) {
      const float* base = nref + ((size_t)(k * 2 + b) * 160) * LPOS;
      num += base[(size_t)(151 + c) * LPOS + i];
      den += base[(size_t)155 * LPOS + i];
    }
    out[t] = num / den;
  } else {                                // warped_ref_seg [2][151][4096]
    int t2 = t - 65536;
    int b = t2 / 618496;
    int rr = t2 % 618496;
    int c = rr >> 12, i = rr & 4095;
    float num = 0.f, den = 0.f;
    for (int k = 0; k < nchunks; ++k) {
      const float* base = nref + ((size_t)(k * 2 + b) * 160) * LPOS;
      num += base[(size_t)c * LPOS + i];
      den += base[(size_t)155 * LPOS + i];
    }
    out[t] = num / den;
  }
}

extern "C" void kernel_launch(void* const* d_in, const int* in_sizes, int n_in,
                              void* d_out, int out_size, void* d_ws, size_t ws_size,
                              hipStream_t stream) {
  const float* trg  = (const float*)d_in[0];
  const float* srcp = (const float*)d_in[1];
  const float* refp = (const float*)d_in[2];
  const float* sfeat = (const float*)d_in[3];
  const float* rfeat = (const float*)d_in[4];
  const float* rsem  = (const float*)d_in[5];
  float* out = (float*)d_out;

  char* ws = (char*)d_ws;
  size_t o = 0;
  auto alloc = [&](size_t bytes) -> char* {
    char* p = ws + o;
    o += (bytes + 255) & ~(size_t)255;
    return p;
  };
  u16* qn  = (u16*)alloc(2ull * LPOS * CDIM * 2);
  u16* ksn = (u16*)alloc(2ull * LPOS * CDIM * 2);
  u16* krn = (u16*)alloc(2ull * LPOS * CDIM * 2);
  u16* vs  = (u16*)alloc(2ull * 32 * LPOS * 2);
  u16* vr  = (u16*)alloc(2ull * 192 * LPOS * 2);
  float* mArr = (float*)alloc(3ull * 2 * LPOS * 4);
  float* iArr = (float*)alloc(3ull * 2 * LPOS * 4);

  size_t fixed = o;
  int nchunks = 4;
  while (nchunks > 1) {
    size_t need = fixed + 512 +
                  (size_t)nchunks * 2 * 8 * LPOS * 4 +
                  (size_t)nchunks * 2 * 160 * LPOS * 4;
    if (need <= ws_size) break;
    nchunks >>= 1;
  }
  float* nsrc = (float*)alloc((size_t)nchunks * 2 * 8 * LPOS * 4);
  float* nref = (float*)alloc((size_t)nchunks * 2 * 160 * LPOS * 4);

  hipLaunchKernelGGL(norm_stats, dim3(96), dim3(256), 0, stream,
                     trg, srcp, refp, mArr, iArr);
  hipLaunchKernelGGL(norm_transpose, dim3(1536), dim3(256), 0, stream,
                     trg, srcp, refp, mArr, iArr, qn, ksn, krn);
  hipLaunchKernelGGL(build_v, dim3(6144), dim3(256), 0, stream,
                     sfeat, rfeat, rsem, vs, vr);
  hipLaunchKernelGGL(flash, dim3(128 * nchunks), dim3(256), 0, stream,
                     qn, ksn, krn, vs, vr, nsrc, nref, nchunks);
  hipLaunchKernelGGL(finalize, dim3(5088), dim3(256), 0, stream,
                     nsrc, nref, out, nchunks);
}